// Round 2
// baseline (992.386 us; speedup 1.0000x reference)
//
#include <hip/hip_runtime.h>

// Attention fwd, fp32 I/O, bf16 MFMA internals.
// x[8,1024,1024] f32, w_qkv[1024,3072] f32, w_proj[1024,1024] f32, b_proj[1024] f32
// Outputs (concat in d_out, fp32): out[8,1024,1024] then attn[8,16,1024,1024]
// B=8, N=1024, C=1024, H=16, hd=64, scale=0.125

typedef unsigned short ushort_t;
typedef __bf16 bf16x8 __attribute__((ext_vector_type(8)));
typedef float floatx4 __attribute__((ext_vector_type(4)));

__device__ __forceinline__ ushort_t f2bf(float f) {
    __bf16 h = (__bf16)f;  // RNE
    return *(ushort_t*)&h;
}

// ---------------------------------------------------------------- transpose + cvt
// out[n][k] = (bf16) in[k][n]; in: rows x cols fp32, out: cols x rows bf16.
__global__ void transpose_f32_bf16(const float* __restrict__ in, ushort_t* __restrict__ out,
                                   int rows, int cols) {
    __shared__ ushort_t tile[32][33];
    int bx = blockIdx.x * 32;  // col base of input
    int by = blockIdx.y * 32;  // row base of input
    int tx = threadIdx.x;
    for (int i = threadIdx.y; i < 32; i += 8)
        tile[i][tx] = f2bf(in[(long)(by + i) * cols + bx + tx]);
    __syncthreads();
    for (int i = threadIdx.y; i < 32; i += 8)
        out[(long)(bx + i) * rows + by + tx] = tile[tx][i];
}

// ---------------------------------------------------------------- GEMM (Bt input)
// C[M][Nc] = A[M][K] @ Bt[Nc][K]^T, 128x128 tile, BK=32, 256 thr (4 waves, 2x2 of 64x64).
// AFP32: A is fp32 (converted to bf16 during staging); else A is bf16.
// MODE 0: scatter epilogue into q[B,H,N,64], k[B,H,N,64], vt[B,H,64,N] (bf16; qkv base = out_p)
// MODE 1: fp32 out_p[m][n] = acc + bias[n]
template <int AFP32>
__device__ __forceinline__ bf16x8 load_a8(const void* A_, long off) {
    if (AFP32) {
        const float* p = (const float*)A_ + off;
        floatx4 f0 = *(const floatx4*)p;
        floatx4 f1 = *(const floatx4*)(p + 4);
        bf16x8 r;
#pragma unroll
        for (int i = 0; i < 4; i++) { r[i] = (__bf16)f0[i]; r[i + 4] = (__bf16)f1[i]; }
        return r;
    } else {
        return *(const bf16x8*)((const ushort_t*)A_ + off);
    }
}

template <int MODE, int AFP32>
__global__ __launch_bounds__(256, 3)
void gemm_bt(const void* __restrict__ A, const ushort_t* __restrict__ Bt,
             int M, int Nc, int K,
             void* __restrict__ out_p, const float* __restrict__ bias) {
    __shared__ ushort_t As[128 * 32];
    __shared__ ushort_t Bs[128 * 32];
    const int tid  = threadIdx.x;
    const int wave = tid >> 6, lane = tid & 63;
    const int quad = lane >> 4, l16 = lane & 15;
    const int bm = blockIdx.y * 128, bn = blockIdx.x * 128;
    const int wm = (wave & 1) * 64, wn = (wave >> 1) * 64;

    floatx4 acc[4][4] = {};

    const int c0 = tid, c1 = tid + 256;
    const int row0 = c0 >> 2, kk0 = (c0 & 3) * 8;
    const int row1 = c1 >> 2, kk1 = (c1 & 3) * 8;

    for (int k0 = 0; k0 < K; k0 += 32) {
        bf16x8 a0 = load_a8<AFP32>(A, (long)(bm + row0) * K + k0 + kk0);
        bf16x8 a1 = load_a8<AFP32>(A, (long)(bm + row1) * K + k0 + kk1);
        bf16x8 b0 = *(const bf16x8*)(Bt + (long)(bn + row0) * K + k0 + kk0);
        bf16x8 b1 = *(const bf16x8*)(Bt + (long)(bn + row1) * K + k0 + kk1);
        __syncthreads();  // prev iteration fully consumed LDS
        *(bf16x8*)&As[c0 * 8] = a0;
        *(bf16x8*)&As[c1 * 8] = a1;
        *(bf16x8*)&Bs[c0 * 8] = b0;
        *(bf16x8*)&Bs[c1 * 8] = b1;
        __syncthreads();
        bf16x8 af[4], bfr[4];
#pragma unroll
        for (int i = 0; i < 4; i++) {
            af[i]  = *(const bf16x8*)&As[(wm + i * 16 + l16) * 32 + quad * 8];
            bfr[i] = *(const bf16x8*)&Bs[(wn + i * 16 + l16) * 32 + quad * 8];
        }
#pragma unroll
        for (int mi = 0; mi < 4; mi++)
#pragma unroll
            for (int ni = 0; ni < 4; ni++)
                acc[mi][ni] = __builtin_amdgcn_mfma_f32_16x16x32_bf16(af[mi], bfr[ni], acc[mi][ni], 0, 0, 0);
    }

    // epilogue. C/D layout: col = lane&15, row = quad*4 + reg (m89-verified)
    if (MODE == 0) {
        ushort_t* qb  = (ushort_t*)out_p;
        ushort_t* kb  = qb + (size_t)8388608;
        ushort_t* vtb = qb + (size_t)16777216;
#pragma unroll
        for (int ni = 0; ni < 4; ni++) {
            int n = bn + wn + ni * 16 + l16;
            int t = n >> 10, c = n & 1023, h = c >> 6, d = c & 63;
#pragma unroll
            for (int mi = 0; mi < 4; mi++) {
                floatx4 v = acc[mi][ni];
#pragma unroll
                for (int r = 0; r < 4; r++) {
                    int m = bm + wm + mi * 16 + quad * 4 + r;
                    int b = m >> 10, tok = m & 1023;
                    long bh = (long)b * 16 + h;
                    ushort_t val = f2bf(v[r]);
                    if (t == 0)      qb[(bh * 1024 + tok) * 64 + d] = val;
                    else if (t == 1) kb[(bh * 1024 + tok) * 64 + d] = val;
                    else             vtb[(bh * 64 + d) * 1024 + tok] = val;
                }
            }
        }
    } else {
        float* outf = (float*)out_p;
#pragma unroll
        for (int ni = 0; ni < 4; ni++) {
            int n = bn + wn + ni * 16 + l16;
            float bv = bias[n];
#pragma unroll
            for (int mi = 0; mi < 4; mi++) {
                floatx4 v = acc[mi][ni];
#pragma unroll
                for (int r = 0; r < 4; r++) {
                    int m = bm + wm + mi * 16 + quad * 4 + r;
                    outf[(long)m * Nc + n] = v[r] + bv;
                }
            }
        }
    }
}

// ---------------------------------------------------------------- fused attention
// grid: 8192 blocks = (bh in [0,128)) x (64 q-tiles of 16 rows); 256 threads (4 waves).
// S[16][1024] fp32 resident in LDS (row stride 1028 to spread banks).
__global__ __launch_bounds__(256, 2)
void attn_fused(const ushort_t* __restrict__ q, const ushort_t* __restrict__ k,
                const ushort_t* __restrict__ vt, float* __restrict__ attn_out,
                ushort_t* __restrict__ ctx) {
    constexpr int SSTR = 1028;
    __shared__ float S[16 * SSTR];
    __shared__ float red_m[16];
    __shared__ float red_il[16];

    const int bh = blockIdx.x >> 6;       // b*16 + h
    const int qt = blockIdx.x & 63;
    const int qbase = qt * 16;
    const int tid = threadIdx.x;
    const int wave = tid >> 6, lane = tid & 63;
    const int quad = lane >> 4, l16 = lane & 15;

    // ---- Phase 1: S = (Q @ K^T) * scale, keys split across 4 waves
    const ushort_t* qrow = q + ((long)bh * 1024 + qbase + l16) * 64 + quad * 8;
    bf16x8 aq0 = *(const bf16x8*)(qrow);
    bf16x8 aq1 = *(const bf16x8*)(qrow + 32);

    const int key0 = wave * 256;
    const ushort_t* kp = k + ((long)bh * 1024 + key0 + l16) * 64 + quad * 8;
    bf16x8 bk0 = *(const bf16x8*)(kp);
    bf16x8 bk1 = *(const bf16x8*)(kp + 32);

    for (int kt = 0; kt < 16; kt++) {
        int ktn = (kt + 1 < 16) ? kt + 1 : 15;
        const ushort_t* npk = kp + (long)ktn * 1024;  // 16 keys * 64
        bf16x8 nb0 = *(const bf16x8*)(npk);
        bf16x8 nb1 = *(const bf16x8*)(npk + 32);
        floatx4 s4 = {0.f, 0.f, 0.f, 0.f};
        s4 = __builtin_amdgcn_mfma_f32_16x16x32_bf16(aq0, bk0, s4, 0, 0, 0);
        s4 = __builtin_amdgcn_mfma_f32_16x16x32_bf16(aq1, bk1, s4, 0, 0, 0);
        int keyc = key0 + kt * 16 + l16;
#pragma unroll
        for (int r = 0; r < 4; r++)
            S[(quad * 4 + r) * SSTR + keyc] = s4[r] * 0.125f;
        bk0 = nb0; bk1 = nb1;
    }
    __syncthreads();

    // ---- Phase 2a: row max + sumexp (16 threads per row)
    {
        int row = tid >> 4, sub = tid & 15;
        float m = -1e30f;
        for (int i = sub; i < 1024; i += 16) m = fmaxf(m, S[row * SSTR + i]);
#pragma unroll
        for (int o = 1; o < 16; o <<= 1) m = fmaxf(m, __shfl_xor(m, o, 64));
        float l = 0.f;
        for (int i = sub; i < 1024; i += 16) l += __expf(S[row * SSTR + i] - m);
#pragma unroll
        for (int o = 1; o < 16; o <<= 1) l += __shfl_xor(l, o, 64);
        if (sub == 0) { red_m[row] = m; red_il[row] = 1.0f / l; }
    }
    __syncthreads();

    // ---- Phase 2b: p = exp(s-m)/l; write attn (fp32, float4), keep p fp32 in LDS
    float* aout = attn_out + ((long)bh * 1024 + qbase) * 1024;
    for (int idx = tid; idx < 16 * 256; idx += 256) {
        int r = idx >> 8, k4 = (idx & 255) * 4;
        float m = red_m[r], il = red_il[r];
        floatx4 pv;
#pragma unroll
        for (int j = 0; j < 4; j++) {
            float p = __expf(S[r * SSTR + k4 + j] - m) * il;
            S[r * SSTR + k4 + j] = p;
            pv[j] = p;
        }
        *(floatx4*)&aout[(long)r * 1024 + k4] = pv;
    }
    __syncthreads();

    // ---- Phase 3: context = P @ V. wave w owns d-cols [w*16, w*16+16), K=1024 keys
    floatx4 o4 = {0.f, 0.f, 0.f, 0.f};
    const ushort_t* vrow = vt + ((long)bh * 64 + wave * 16 + l16) * 1024 + quad * 8;
    for (int ks = 0; ks < 32; ks++) {
        const float* sp = &S[l16 * SSTR + ks * 32 + quad * 8];
        floatx4 p0 = *(const floatx4*)(sp);
        floatx4 p1 = *(const floatx4*)(sp + 4);
        bf16x8 pa;
#pragma unroll
        for (int i = 0; i < 4; i++) { pa[i] = (__bf16)p0[i]; pa[i + 4] = (__bf16)p1[i]; }
        bf16x8 vb = *(const bf16x8*)(vrow + ks * 32);
        o4 = __builtin_amdgcn_mfma_f32_16x16x32_bf16(pa, vb, o4, 0, 0, 0);
    }
    // write ctx[B,N,C] bf16: row = qbase + quad*4 + r, col = h*64 + wave*16 + l16
    int b = bh >> 4, h = bh & 15;
    ushort_t* cp = ctx + ((long)b * 1024 + qbase) * 1024 + h * 64 + wave * 16 + l16;
#pragma unroll
    for (int r = 0; r < 4; r++)
        cp[(long)(quad * 4 + r) * 1024] = f2bf(o4[r]);
}

// ---------------------------------------------------------------- launch
extern "C" void kernel_launch(void* const* d_in, const int* in_sizes, int n_in,
                              void* d_out, int out_size, void* d_ws, size_t ws_size,
                              hipStream_t stream) {
    const float* x      = (const float*)d_in[0];
    const float* w_qkv  = (const float*)d_in[1];
    const float* w_proj = (const float*)d_in[2];
    const float* b_proj = (const float*)d_in[3];

    float* out  = (float*)d_out;                             // [8,1024,1024] fp32
    float* attn = out + (size_t)8 * 1024 * 1024;             // [8,16,1024,1024] fp32

    ushort_t* ws     = (ushort_t*)d_ws;
    ushort_t* q      = ws;                                   //  8M elts bf16 [B,H,N,64]
    ushort_t* kk     = ws + (size_t)8  * 1024 * 1024;        //  8M elts bf16 [B,H,N,64]
    ushort_t* vt     = ws + (size_t)16 * 1024 * 1024;        //  8M elts bf16 [B,H,64,N]
    ushort_t* ctx    = ws + (size_t)24 * 1024 * 1024;        //  8M elts bf16 [B,N,C]
    ushort_t* wqkvt  = ws + (size_t)32 * 1024 * 1024;        //  3M elts bf16 [3072,1024]
    ushort_t* wprojt = ws + (size_t)35 * 1024 * 1024;        //  1M elts bf16 [1024,1024]

    transpose_f32_bf16<<<dim3(96, 32), dim3(32, 8), 0, stream>>>(w_qkv, wqkvt, 1024, 3072);
    transpose_f32_bf16<<<dim3(32, 32), dim3(32, 8), 0, stream>>>(w_proj, wprojt, 1024, 1024);

    // QKV: [8192,1024] @ [1024,3072], A fp32
    gemm_bt<0, 1><<<dim3(24, 64), dim3(256), 0, stream>>>(x, wqkvt, 8192, 3072, 1024, q, (const float*)nullptr);

    // attention: 128 (b,h) * 64 q-tiles
    attn_fused<<<dim3(8192), dim3(256), 0, stream>>>(q, kk, vt, attn, ctx);

    // proj: [8192,1024] @ [1024,1024] + bias, A bf16, out fp32
    gemm_bt<1, 0><<<dim3(8, 64), dim3(256), 0, stream>>>(ctx, wprojt, 8192, 1024, 1024, out, b_proj);
}